// Round 7
// baseline (232.077 us; speedup 1.0000x reference)
//
#include <hip/hip_runtime.h>
#include <cstddef>
#include <cstdint>

// ---------------- problem constants ----------------
#define cB   512
#define cV   5023
#define cS   100
#define cE   50
#define cJ   5
#define cLD  17
#define cLF  68

#define cV3    15069       // V*3
#define cNPAD  15072       // 157*96 padded N

#define OUT_V  ((size_t)cB * cV * 3)
#define OUT_L  ((size_t)cB * cLF * 3)

// ws layout (dword offsets)
#define WS_PDT    ((size_t)0)                      // pdT16: 15072*18 dwords (bf16 x2)
#define WS_ATM    (WS_PDT + 271296)                // 512*96 dwords
#define WS_JS2    (WS_ATM + 49152)                 // 2432 floats
#define WS_AREL   (WS_JS2 + 2432)                  // 512*60 floats
#define WS_YROT   (WS_AREL + 30720)                // 512 ints
#define WS_JSPART (WS_YROT + 512)                  // 628*2272 floats

typedef __attribute__((ext_vector_type(8))) short short8;
typedef __attribute__((ext_vector_type(4))) float f32x4;

// fp32 -> bf16 round-to-nearest-even
__device__ __forceinline__ unsigned short f2bf(float x) {
  unsigned int u = __float_as_uint(x);
  u = (u + 0x7fffu + ((u >> 16) & 1u)) >> 16;
  return (unsigned short)u;
}

// ---------------- rodrigues (matches jax reference in fp32) ----------------
__device__ __forceinline__ void rodrigues9(float rx, float ry, float rz, float* R) {
  float a0 = rx + 1e-8f, a1 = ry + 1e-8f, a2 = rz + 1e-8f;
  float angle = sqrtf(a0 * a0 + a1 * a1 + a2 * a2);
  float inv = 1.0f / angle;
  float x = rx * inv, y = ry * inv, z = rz * inv;
  float s = sinf(angle), c = cosf(angle);
  float t = 1.0f - c;
  float xy = x * y, xz = x * z, yz = y * z;
  R[0] = 1.0f - t * (y * y + z * z);
  R[1] = -s * z + t * xy;
  R[2] =  s * y + t * xz;
  R[3] =  s * z + t * xy;
  R[4] = 1.0f - t * (x * x + z * z);
  R[5] = -s * x + t * yz;
  R[6] = -s * y + t * xz;
  R[7] =  s * x + t * yz;
  R[8] = 1.0f - t * (x * x + y * y);
}

// ---------------- k_aux: blocks 0..627 JS partials (8 v each); 628..863 pd transpose ----
__global__ __launch_bounds__(512) void k_aux(
    const float* __restrict__ sd, const float* __restrict__ pd,
    const float* __restrict__ jreg, const float* __restrict__ vt,
    unsigned int* __restrict__ pdt16_u, float* __restrict__ JSpart) {
  __shared__ unsigned short T[2304];
  const int t = threadIdx.x;
  const int bid = blockIdx.x;
  if (bid < 628) {
    if (t >= 453) return;
    int c = t / 151, l = t - c * 151;
    int v0 = bid * 8;
    float acc[5] = {0.f, 0.f, 0.f, 0.f, 0.f};
#pragma unroll
    for (int vi = 0; vi < 8; ++vi) {
      int v = v0 + vi;
      bool ok = (v < cV);
      int vc = ok ? v : 0;
      float x;
      if (l < 150) x = ok ? sd[(size_t)(v * 3 + c) * 150 + l] : 0.f;
      else         x = ok ? vt[v * 3 + c] : 0.f;
#pragma unroll
      for (int j = 0; j < 5; ++j)
        acc[j] = fmaf(jreg[j * cV + vc], x, acc[j]);
    }
#pragma unroll
    for (int j = 0; j < 5; ++j)
      JSpart[(size_t)bid * 2272 + (j * 3 + c) * 151 + l] = acc[j];
  } else {
    const int n0 = (bid - 628) * 64;
    for (int e = t; e < 2304; e += 512) {
      int kk = e >> 6, ln = e & 63;
      int n = n0 + ln;
      float v = (n < cV3) ? pd[(size_t)kk * cV3 + n] : 0.f;
      T[ln * 36 + kk] = f2bf(v);
    }
    __syncthreads();
    for (int e = t; e < 1152; e += 512) {
      int ln = e / 18, d = e - ln * 18;
      int n = n0 + ln;
      if (n < cNPAD) {
        unsigned int wv = (unsigned int)T[ln * 36 + 2 * d] |
                          ((unsigned int)T[ln * 36 + 2 * d + 1] << 16);
        pdt16_u[(size_t)n * 18 + d] = wv;
      }
    }
  }
}

// ---------------- k_jsred: 628 partials -> JS2[l][16]; 8 threads per element ----------------
__global__ __launch_bounds__(256) void k_jsred(const float* __restrict__ JSpart,
                                               float* __restrict__ JS2) {
  __shared__ float red[256];
  const int t = threadIdx.x;
  const int e = blockIdx.x * 32 + (t & 31);
  const int pg = t >> 5;
  float s = 0.f;
  if (e < 2265) {
#pragma unroll 8
    for (int p = pg; p < 628; p += 8)
      s += JSpart[(size_t)p * 2272 + e];
  }
  red[t] = s;
  __syncthreads();
  if (t < 128) red[t] += red[t + 128];
  __syncthreads();
  if (t < 64) red[t] += red[t + 64];
  __syncthreads();
  if (t < 32) {
    float v = red[t] + red[t + 32];
    if (e < 2265) {
      int jc = e / 151, l = e - jc * 151;
      JS2[l * 16 + jc] = v;
    }
  }
}

// ---------------- k_batch: joints, rot mats, chain, A_rel, y_rot + ATm bf16 rows ----------
__global__ __launch_bounds__(256) void k_batch(
    const float* __restrict__ shp, const float* __restrict__ expr,
    const float* __restrict__ pose, const float* __restrict__ eyep,
    const float* __restrict__ JS2g, float* __restrict__ Arel,
    int* __restrict__ yrot, unsigned int* __restrict__ atm_u) {
  __shared__ float js2[151 * 16];
  __shared__ float sb[32 * 153];
  __shared__ float pfs[32 * 36];
  const int t = threadIdx.x;
  const int b0 = blockIdx.x * 32;
  for (int i = t; i < 151 * 16; i += 256) js2[i] = JS2g[i];
  for (int e = t; e < 3200; e += 256) {
    int bl = e / 100, l = e - bl * 100;
    sb[bl * 153 + l] = shp[(size_t)(b0 + bl) * 100 + l];
  }
  for (int e = t; e < 1600; e += 256) {
    int bl = e / 50, l = e - bl * 50;
    sb[bl * 153 + 100 + l] = expr[(size_t)(b0 + bl) * 50 + l];
  }
  __syncthreads();

  if (t < 32) {
    int b = b0 + t;
    float jnt[5][3];
    {
      const f32x4* J4 = (const f32x4*)(js2 + 150 * 16);
      f32x4 A = J4[0], Bq = J4[1], Cq = J4[2], Dq = J4[3];
      jnt[0][0] = A.x;  jnt[0][1] = A.y;  jnt[0][2] = A.z;
      jnt[1][0] = A.w;  jnt[1][1] = Bq.x; jnt[1][2] = Bq.y;
      jnt[2][0] = Bq.z; jnt[2][1] = Bq.w; jnt[2][2] = Cq.x;
      jnt[3][0] = Cq.y; jnt[3][1] = Cq.z; jnt[3][2] = Cq.w;
      jnt[4][0] = Dq.x; jnt[4][1] = Dq.y; jnt[4][2] = Dq.z;
    }
    for (int l = 0; l < 150; ++l) {
      const f32x4* J4 = (const f32x4*)(js2 + l * 16);
      f32x4 A = J4[0], Bq = J4[1], Cq = J4[2], Dq = J4[3];
      float beta = sb[t * 153 + l];
      jnt[0][0] = fmaf(beta, A.x,  jnt[0][0]);
      jnt[0][1] = fmaf(beta, A.y,  jnt[0][1]);
      jnt[0][2] = fmaf(beta, A.z,  jnt[0][2]);
      jnt[1][0] = fmaf(beta, A.w,  jnt[1][0]);
      jnt[1][1] = fmaf(beta, Bq.x, jnt[1][1]);
      jnt[1][2] = fmaf(beta, Bq.y, jnt[1][2]);
      jnt[2][0] = fmaf(beta, Bq.z, jnt[2][0]);
      jnt[2][1] = fmaf(beta, Bq.w, jnt[2][1]);
      jnt[2][2] = fmaf(beta, Cq.x, jnt[2][2]);
      jnt[3][0] = fmaf(beta, Cq.y, jnt[3][0]);
      jnt[3][1] = fmaf(beta, Cq.z, jnt[3][1]);
      jnt[3][2] = fmaf(beta, Cq.w, jnt[3][2]);
      jnt[4][0] = fmaf(beta, Dq.x, jnt[4][0]);
      jnt[4][1] = fmaf(beta, Dq.y, jnt[4][1]);
      jnt[4][2] = fmaf(beta, Dq.z, jnt[4][2]);
    }
    float fp[5][3];
    fp[0][0] = pose[b * 6 + 0]; fp[0][1] = pose[b * 6 + 1]; fp[0][2] = pose[b * 6 + 2];
    fp[1][0] = 0.f; fp[1][1] = 0.f; fp[1][2] = 0.f;
    fp[2][0] = pose[b * 6 + 3]; fp[2][1] = pose[b * 6 + 4]; fp[2][2] = pose[b * 6 + 5];
    fp[3][0] = eyep[b * 6 + 0]; fp[3][1] = eyep[b * 6 + 1]; fp[3][2] = eyep[b * 6 + 2];
    fp[4][0] = eyep[b * 6 + 3]; fp[4][1] = eyep[b * 6 + 4]; fp[4][2] = eyep[b * 6 + 5];
    float R[5][9];
#pragma unroll
    for (int j = 0; j < 5; ++j) rodrigues9(fp[j][0], fp[j][1], fp[j][2], R[j]);
#pragma unroll
    for (int j = 1; j < 5; ++j)
#pragma unroll
      for (int r = 0; r < 9; ++r) {
        float id = (r == 0 || r == 4 || r == 8) ? 1.f : 0.f;
        pfs[t * 36 + (j - 1) * 9 + r] = R[j][r] - id;
      }
    float rel[5][3];
#pragma unroll
    for (int c = 0; c < 3; ++c) {
      rel[0][c] = jnt[0][c];
      rel[1][c] = jnt[1][c] - jnt[0][c];
      rel[2][c] = jnt[2][c] - jnt[1][c];
      rel[3][c] = jnt[3][c] - jnt[1][c];
      rel[4][c] = jnt[4][c] - jnt[1][c];
    }
    float GR[5][9], Gt[5][3];
#pragma unroll
    for (int r = 0; r < 9; ++r) GR[0][r] = R[0][r];
#pragma unroll
    for (int c = 0; c < 3; ++c) Gt[0][c] = rel[0][c];
    const int par[5] = {0, 0, 1, 1, 1};
#pragma unroll
    for (int j = 1; j < 5; ++j) {
      int p = par[j];
#pragma unroll
      for (int r = 0; r < 3; ++r) {
#pragma unroll
        for (int cc = 0; cc < 3; ++cc)
          GR[j][r * 3 + cc] = GR[p][r * 3 + 0] * R[j][0 + cc] +
                              GR[p][r * 3 + 1] * R[j][3 + cc] +
                              GR[p][r * 3 + 2] * R[j][6 + cc];
        Gt[j][r] = Gt[p][r] + GR[p][r * 3 + 0] * rel[j][0] +
                              GR[p][r * 3 + 1] * rel[j][1] +
                              GR[p][r * 3 + 2] * rel[j][2];
      }
    }
#pragma unroll
    for (int j = 0; j < 5; ++j)
#pragma unroll
      for (int r = 0; r < 3; ++r) {
        float tj = Gt[j][r] - (GR[j][r * 3 + 0] * jnt[j][0] +
                               GR[j][r * 3 + 1] * jnt[j][1] +
                               GR[j][r * 3 + 2] * jnt[j][2]);
        Arel[b * 60 + j * 12 + r * 4 + 0] = GR[j][r * 3 + 0];
        Arel[b * 60 + j * 12 + r * 4 + 1] = GR[j][r * 3 + 1];
        Arel[b * 60 + j * 12 + r * 4 + 2] = GR[j][r * 3 + 2];
        Arel[b * 60 + j * 12 + r * 4 + 3] = tj;
      }
    float Ra[9], Rb[9];
    rodrigues9(fp[1][0], fp[1][1], fp[1][2], Ra);
    rodrigues9(fp[0][0], fp[0][1], fp[0][2], Rb);
    float r00 = Rb[0] * Ra[0] + Rb[1] * Ra[3] + Rb[2] * Ra[6];
    float r10 = Rb[3] * Ra[0] + Rb[4] * Ra[3] + Rb[5] * Ra[6];
    float r20 = Rb[6] * Ra[0] + Rb[7] * Ra[3] + Rb[8] * Ra[6];
    float sy = sqrtf(r00 * r00 + r10 * r10);
    float ydeg = atan2f(-r20, sy) * 57.29577951308232f;
    int y = (int)rintf(fminf(ydeg, 39.0f));
    if (y < 0) y = (y < -39) ? 78 : (39 - y);
    yrot[b] = y;
  }
  __syncthreads();

#pragma unroll
  for (int it = 0; it < 12; ++it) {
    int e = t + it * 256;
    int bl = e / 96, d = e - bl * 96;
    unsigned int wv;
    if (d < 75) {
      wv = (unsigned int)f2bf(sb[bl * 153 + 2 * d]) |
           ((unsigned int)f2bf(sb[bl * 153 + 2 * d + 1]) << 16);
    } else if (d < 93) {
      wv = (unsigned int)f2bf(pfs[bl * 36 + (d - 75) * 2]) |
           ((unsigned int)f2bf(pfs[bl * 36 + (d - 75) * 2 + 1]) << 16);
    } else {
      wv = 0u;
    }
    atm_u[(size_t)(b0 + bl) * 96 + d] = wv;
  }
}

// ---------------- k_main: persistent B tile, 4 mb-tiles per block, b-major epilogue ----------------
// grid 314 = 157 nb x 2 batch-halves. LDS: Bs 38400 + Pf[48][68] 13056 + O[64][49] 12544 = 64000 B.
__global__ __launch_bounds__(256) void k_main(
    const float* __restrict__ sd, const unsigned int* __restrict__ pdt16_u,
    const unsigned short* __restrict__ ATm, const float* __restrict__ Arel,
    const float* __restrict__ vtempl, const float* __restrict__ lbw,
    float* __restrict__ out) {
  __shared__ __align__(16) unsigned char smem[64000];
  unsigned short* Bs = (unsigned short*)smem;
  float* Pf = (float*)(smem + 38400);
  float* Ob = (float*)(smem + 51456);

  const int bid = blockIdx.x;
  const int nb = bid >> 1, mbh = bid & 1;
  const int t = threadIdx.x;
  const int n0 = nb * 96;

  const int w = t >> 6;
  const int wm = w >> 1, wn = w & 1;
  const int L = t & 63, lr = L & 15, lq = L >> 4;
  const int b_loc = t & 63, vgrp = t >> 6;

  // ---- preload per-thread vertex constants (wave-uniform addresses) ----
  float wjv[2][4][5], vtv[2][4][3];
#pragma unroll
  for (int nh = 0; nh < 2; ++nh)
#pragma unroll
    for (int i = 0; i < 4; ++i) {
      int v = nb * 32 + nh * 16 + vgrp * 4 + i;
      bool ok = (v < cV);
#pragma unroll
      for (int j = 0; j < 5; ++j) wjv[nh][i][j] = ok ? lbw[v * 5 + j] : 0.f;
#pragma unroll
      for (int c = 0; c < 3; ++c) vtv[nh][i][c] = ok ? vtempl[v * 3 + c] : 0.f;
    }

  // ---- stage B tile once: sd fp32 -> bf16 rows [96][200] + pdT cols ----
  {
    const float* sbase = sd + (size_t)n0 * 150;
    const int vrows = (cV3 - n0 < 96) ? (cV3 - n0) : 96;
    const int vunits = vrows * 75;
#pragma unroll
    for (int it = 0; it < 29; ++it) {
      int u = t + it * 256;
      if (u < 7200) {
        float fx = 0.f, fy = 0.f;
        if (u < vunits) {
          float2 f2 = *(const float2*)(sbase + 2 * (size_t)u);
          fx = f2.x; fy = f2.y;
        }
        unsigned int wv = (unsigned int)f2bf(fx) | ((unsigned int)f2bf(fy) << 16);
        int row = u / 75, cp = u - row * 75;
        *(unsigned int*)(smem + row * 400 + cp * 4) = wv;
      }
    }
    const unsigned int* pdu = pdt16_u + (size_t)n0 * 18;
#pragma unroll
    for (int it = 0; it < 7; ++it) {
      int u = t + it * 256;
      if (u < 1728) {
        unsigned int wv = pdu[u];
        int row = u / 18, d = u - row * 18;
        *(unsigned int*)(smem + row * 400 + 300 + d * 4) = wv;
      }
    }
#pragma unroll
    for (int it = 0; it < 3; ++it) {
      int u = t + it * 256;
      if (u < 672) {
        int row = u / 7, d = u - row * 7;
        *(unsigned int*)(smem + row * 400 + 372 + d * 4) = 0u;
      }
    }
  }
  __syncthreads();

  // ---- loop over 4 batch tiles ----
#pragma unroll 1
  for (int mh = 0; mh < 4; ++mh) {
    const int mb = mbh * 4 + mh;

    // Arel row for this thread's batch (15 loads, in flight across MFMA)
    const float* qb = Arel + ((size_t)mb * 64 + b_loc) * 60;
    f32x4 ar[15];
#pragma unroll
    for (int r = 0; r < 15; ++r) ar[r] = *(const f32x4*)(qb + 4 * r);

    // MFMA with rolling A prefetch
    f32x4 acc[2][3];
#pragma unroll
    for (int mt = 0; mt < 2; ++mt)
#pragma unroll
      for (int nt = 0; nt < 3; ++nt) acc[mt][nt] = (f32x4){0.f, 0.f, 0.f, 0.f};

    const unsigned short* abase = ATm + ((size_t)mb * 64 + wm * 32 + lr) * 192 + lq * 8;
    short8 af0 = *(const short8*)(abase);
    short8 af1 = *(const short8*)(abase + 16 * 192);
#pragma unroll
    for (int ks = 0; ks < 6; ++ks) {
      short8 nf0, nf1;
      if (ks < 5) {
        nf0 = *(const short8*)(abase + (ks + 1) * 32);
        nf1 = *(const short8*)(abase + 16 * 192 + (ks + 1) * 32);
      }
      const int ko = ks * 32 + lq * 8;
      short8 bf[3];
#pragma unroll
      for (int nt = 0; nt < 3; ++nt)
        bf[nt] = *(const short8*)(Bs + (wn * 48 + nt * 16 + lr) * 200 + ko);
#pragma unroll
      for (int nt = 0; nt < 3; ++nt) {
        acc[0][nt] = __builtin_amdgcn_mfma_f32_16x16x32_bf16(af0, bf[nt], acc[0][nt], 0, 0, 0);
        acc[1][nt] = __builtin_amdgcn_mfma_f32_16x16x32_bf16(af1, bf[nt], acc[1][nt], 0, 0, 0);
      }
      af0 = nf0; af1 = nf1;
    }

    // two n-halves: transpose acc half -> Pf, compute LBS b-major, stream out
#pragma unroll 1
    for (int nh = 0; nh < 2; ++nh) {
      __syncthreads();                      // protect Pf / Ob from previous use
      if (wn == nh) {
#pragma unroll
        for (int mt = 0; mt < 2; ++mt)
#pragma unroll
          for (int nt = 0; nt < 3; ++nt) {
            int n_local = nt * 16 + lr;
            int m = wm * 32 + mt * 16 + lq * 4;
            *(f32x4*)(Pf + n_local * 68 + m) = acc[mt][nt];
          }
      }
      __syncthreads();

#pragma unroll
      for (int i = 0; i < 4; ++i) {
        int vl = vgrp * 4 + i;              // 0..15 local vertex in half
        float px = Pf[(vl * 3 + 0) * 68 + b_loc] + vtv[nh][i][0];
        float py = Pf[(vl * 3 + 1) * 68 + b_loc] + vtv[nh][i][1];
        float pz = Pf[(vl * 3 + 2) * 68 + b_loc] + vtv[nh][i][2];
        float o0 = 0.f, o1 = 0.f, o2 = 0.f;
#pragma unroll
        for (int j = 0; j < 5; ++j) {
          f32x4 q0 = ar[3 * j + 0], q1 = ar[3 * j + 1], q2 = ar[3 * j + 2];
          float s0 = q0.x * px + q0.y * py + q0.z * pz + q0.w;
          float s1 = q1.x * px + q1.y * py + q1.z * pz + q1.w;
          float s2 = q2.x * px + q2.y * py + q2.z * pz + q2.w;
          float wj = wjv[nh][i][j];
          o0 = fmaf(wj, s0, o0);
          o1 = fmaf(wj, s1, o1);
          o2 = fmaf(wj, s2, o2);
        }
        Ob[b_loc * 49 + vl * 3 + 0] = o0;
        Ob[b_loc * 49 + vl * 3 + 1] = o1;
        Ob[b_loc * 49 + vl * 3 + 2] = o2;
      }
      __syncthreads();

      // stream Ob -> out: 64 batches x 48 cols, sequential dword bursts
      const int colbase = n0 + nh * 48;
#pragma unroll
      for (int it2 = 0; it2 < 12; ++it2) {
        int idx = t + it2 * 256;            // < 3072
        int bl = idx / 48, x = idx - bl * 48;
        int col = colbase + x;
        if (col < cV3)
          out[(size_t)(mb * 64 + bl) * cV3 + col] = Ob[bl * 49 + x];
      }
    }
  }
}

// ---------------- k_lmk: barycentric landmark gather, 1 thread per (b, l, which) ----------------
__global__ void k_lmk(const float* __restrict__ verts, const int* __restrict__ faces,
                      const int* __restrict__ lmkf, const float* __restrict__ lmkb,
                      const int* __restrict__ dynf, const float* __restrict__ dynb,
                      const int* __restrict__ fullf, const float* __restrict__ fullb,
                      const int* __restrict__ yrot, float* __restrict__ out) {
  int id = blockIdx.x * 256 + threadIdx.x;
  if (id >= cB * cLF * 2) return;
  int sel = id & 1;
  int r = id >> 1;
  int b = r / cLF, l = r - b * cLF;
  const float* vb = verts + (size_t)b * cV * 3;
  int f; float w0, w1, w2; size_t o;
  if (sel == 0) {
    if (l < cLD) {
      int yb = yrot[b];
      f = dynf[yb * cLD + l];
      const float* bp = dynb + ((size_t)yb * cLD + l) * 3;
      w0 = bp[0]; w1 = bp[1]; w2 = bp[2];
    } else {
      f = lmkf[l - cLD];
      const float* bp = lmkb + (size_t)(l - cLD) * 3;
      w0 = bp[0]; w1 = bp[1]; w2 = bp[2];
    }
    o = OUT_V + ((size_t)b * cLF + l) * 3;
  } else {
    f = fullf[l];
    const float* bp = fullb + (size_t)l * 3;
    w0 = bp[0]; w1 = bp[1]; w2 = bp[2];
    o = OUT_V + OUT_L + ((size_t)b * cLF + l) * 3;
  }
  int i0 = faces[f * 3 + 0] * 3, i1 = faces[f * 3 + 1] * 3, i2 = faces[f * 3 + 2] * 3;
  out[o + 0] = w0 * vb[i0 + 0] + w1 * vb[i1 + 0] + w2 * vb[i2 + 0];
  out[o + 1] = w0 * vb[i0 + 1] + w1 * vb[i1 + 1] + w2 * vb[i2 + 1];
  out[o + 2] = w0 * vb[i0 + 2] + w1 * vb[i1 + 2] + w2 * vb[i2 + 2];
}

// ---------------- launch ----------------
extern "C" void kernel_launch(void* const* d_in, const int* in_sizes, int n_in,
                              void* d_out, int out_size, void* d_ws, size_t ws_size,
                              hipStream_t stream) {
  (void)in_sizes; (void)n_in; (void)out_size; (void)ws_size;
  const float* shp  = (const float*)d_in[0];
  const float* expr = (const float*)d_in[1];
  const float* pose = (const float*)d_in[2];
  const float* eyep = (const float*)d_in[3];
  const float* vt   = (const float*)d_in[4];
  const float* sd   = (const float*)d_in[5];
  const float* pd   = (const float*)d_in[6];
  const float* jreg = (const float*)d_in[7];
  const float* lbw  = (const float*)d_in[8];
  const int*   fcs  = (const int*)d_in[9];
  const int*   lmkf = (const int*)d_in[10];
  const float* lmkb = (const float*)d_in[11];
  const int*   dynf = (const int*)d_in[12];
  const float* dynb = (const float*)d_in[13];
  const int*   fullf= (const int*)d_in[14];
  const float* fullb= (const float*)d_in[15];
  float* out = (float*)d_out;
  float* ws  = (float*)d_ws;

  unsigned int*   pdt16 = (unsigned int*)(ws + WS_PDT);
  unsigned short* ATm   = (unsigned short*)(ws + WS_ATM);
  float* JS2    = ws + WS_JS2;
  float* Arel   = ws + WS_AREL;
  int*   yrot   = (int*)(ws + WS_YROT);
  float* JSpart = ws + WS_JSPART;

  k_aux<<<864, 512, 0, stream>>>(sd, pd, jreg, vt, pdt16, JSpart);
  k_jsred<<<71, 256, 0, stream>>>(JSpart, JS2);
  k_batch<<<16, 256, 0, stream>>>(shp, expr, pose, eyep, JS2, Arel, yrot,
                                  (unsigned int*)ATm);
  k_main<<<314, 256, 0, stream>>>(sd, pdt16, ATm, Arel, vt, lbw, out);
  k_lmk<<<272, 256, 0, stream>>>(out, fcs, lmkf, lmkb, dynf, dynb, fullf, fullb, yrot, out);
}

// Round 8
// 184.353 us; speedup vs baseline: 1.2589x; 1.2589x over previous
//
#include <hip/hip_runtime.h>
#include <cstddef>
#include <cstdint>

// ---------------- problem constants ----------------
#define cB   512
#define cV   5023
#define cS   100
#define cE   50
#define cJ   5
#define cLD  17
#define cLF  68

#define cV3    15069       // V*3
#define cNPAD  15072       // 157*96 padded N

#define OUT_V  ((size_t)cB * cV * 3)
#define OUT_L  ((size_t)cB * cLF * 3)

// ws layout (dword offsets)
#define WS_BTN    ((size_t)0)                      // 15072*96 dwords (bf16 x2)
#define WS_ATM    (WS_BTN + (size_t)cNPAD * 96)    // 512*96 dwords
#define WS_JS2    (WS_ATM + 49152)                 // 2432 floats
#define WS_AREL   (WS_JS2 + 2432)                  // 512*60 floats
#define WS_YROT   (WS_AREL + 30720)                // 512 ints
#define WS_JSPART (WS_YROT + 512)                  // 628*2272 floats

typedef __attribute__((ext_vector_type(8))) short short8;
typedef __attribute__((ext_vector_type(4))) float f32x4;

// fp32 -> bf16 round-to-nearest-even
__device__ __forceinline__ unsigned short f2bf(float x) {
  unsigned int u = __float_as_uint(x);
  u = (u + 0x7fffu + ((u >> 16) & 1u)) >> 16;
  return (unsigned short)u;
}

// ---------------- rodrigues (matches jax reference in fp32) ----------------
__device__ __forceinline__ void rodrigues9(float rx, float ry, float rz, float* R) {
  float a0 = rx + 1e-8f, a1 = ry + 1e-8f, a2 = rz + 1e-8f;
  float angle = sqrtf(a0 * a0 + a1 * a1 + a2 * a2);
  float inv = 1.0f / angle;
  float x = rx * inv, y = ry * inv, z = rz * inv;
  float s = sinf(angle), c = cosf(angle);
  float t = 1.0f - c;
  float xy = x * y, xz = x * z, yz = y * z;
  R[0] = 1.0f - t * (y * y + z * z);
  R[1] = -s * z + t * xy;
  R[2] =  s * y + t * xz;
  R[3] =  s * z + t * xy;
  R[4] = 1.0f - t * (x * x + z * z);
  R[5] = -s * x + t * yz;
  R[6] = -s * y + t * xz;
  R[7] =  s * x + t * yz;
  R[8] = 1.0f - t * (x * x + y * y);
}

// ---------------- k_aux: blocks 0..627 JS partials; 628..863 build bf16 BTn rows ----------
// BTn[n][192]: cols 0..149 = sd[n][:], 150..185 = pd^T[n][:], rest 0.
__global__ __launch_bounds__(512) void k_aux(
    const float* __restrict__ sd, const float* __restrict__ pd,
    const float* __restrict__ jreg, const float* __restrict__ vt,
    unsigned int* __restrict__ btn_u, float* __restrict__ JSpart) {
  __shared__ __align__(16) unsigned char sm[44032];  // sdt 64*152*4 @0; pdt 64*38*2 @38912
  float* sdt = (float*)sm;
  unsigned short* pdt = (unsigned short*)(sm + 38912);
  const int t = threadIdx.x;
  const int bid = blockIdx.x;
  if (bid < 628) {
    if (t >= 453) return;
    int c = t / 151, l = t - c * 151;
    int v0 = bid * 8;
    float acc[5] = {0.f, 0.f, 0.f, 0.f, 0.f};
#pragma unroll
    for (int vi = 0; vi < 8; ++vi) {
      int v = v0 + vi;
      bool ok = (v < cV);
      int vc = ok ? v : 0;
      float x;
      if (l < 150) x = ok ? sd[(size_t)(v * 3 + c) * 150 + l] : 0.f;
      else         x = ok ? vt[v * 3 + c] : 0.f;
#pragma unroll
      for (int j = 0; j < 5; ++j)
        acc[j] = fmaf(jreg[j * cV + vc], x, acc[j]);
    }
#pragma unroll
    for (int j = 0; j < 5; ++j)
      JSpart[(size_t)bid * 2272 + (j * 3 + c) * 151 + l] = acc[j];
  } else {
    const int n0 = (bid - 628) * 64;
    // sd rows (linear, coalesced)
    for (int idx = t; idx < 9600; idx += 512) {
      size_t g = (size_t)n0 * 150 + idx;
      float v = (g < (size_t)cV3 * 150) ? sd[g] : 0.f;
      int row = idx / 150, col = idx - row * 150;
      sdt[row * 152 + col] = v;
    }
    // pd columns (coalesced over n)
    for (int e = t; e < 2304; e += 512) {
      int kk = e >> 6, ln = e & 63;
      int n = n0 + ln;
      pdt[ln * 38 + kk] = f2bf((n < cV3) ? pd[(size_t)kk * cV3 + n] : 0.f);
    }
    __syncthreads();
    // emit BTn rows (96 dwords each), coalesced
    for (int e = t; e < 6144; e += 512) {
      int row = e / 96, d = e - row * 96;
      int n = n0 + row;
      if (n < cNPAD) {
        unsigned int wv;
        if (d < 75) {
          wv = (unsigned int)f2bf(sdt[row * 152 + 2 * d]) |
               ((unsigned int)f2bf(sdt[row * 152 + 2 * d + 1]) << 16);
        } else if (d < 93) {
          int p = (d - 75) * 2;
          wv = (unsigned int)pdt[row * 38 + p] |
               ((unsigned int)pdt[row * 38 + p + 1] << 16);
        } else {
          wv = 0u;
        }
        btn_u[(size_t)n * 96 + d] = wv;
      }
    }
  }
}

// ---------------- k_jsred: 628 partials -> JS2[l][16]; 8 threads per element ----------------
__global__ __launch_bounds__(256) void k_jsred(const float* __restrict__ JSpart,
                                               float* __restrict__ JS2) {
  __shared__ float red[256];
  const int t = threadIdx.x;
  const int e = blockIdx.x * 32 + (t & 31);
  const int pg = t >> 5;
  float s = 0.f;
  if (e < 2265) {
#pragma unroll 8
    for (int p = pg; p < 628; p += 8)
      s += JSpart[(size_t)p * 2272 + e];
  }
  red[t] = s;
  __syncthreads();
  if (t < 128) red[t] += red[t + 128];
  __syncthreads();
  if (t < 64) red[t] += red[t + 64];
  __syncthreads();
  if (t < 32) {
    float v = red[t] + red[t + 32];
    if (e < 2265) {
      int jc = e / 151, l = e - jc * 151;
      JS2[l * 16 + jc] = v;
    }
  }
}

// ---------------- k_batch: joints, rot mats, chain, A_rel, y_rot + ATm bf16 rows ----------
__global__ __launch_bounds__(256) void k_batch(
    const float* __restrict__ shp, const float* __restrict__ expr,
    const float* __restrict__ pose, const float* __restrict__ eyep,
    const float* __restrict__ JS2g, float* __restrict__ Arel,
    int* __restrict__ yrot, unsigned int* __restrict__ atm_u) {
  __shared__ float js2[151 * 16];
  __shared__ float sb[32 * 153];
  __shared__ float pfs[32 * 36];
  const int t = threadIdx.x;
  const int b0 = blockIdx.x * 32;
  for (int i = t; i < 151 * 16; i += 256) js2[i] = JS2g[i];
  for (int e = t; e < 3200; e += 256) {
    int bl = e / 100, l = e - bl * 100;
    sb[bl * 153 + l] = shp[(size_t)(b0 + bl) * 100 + l];
  }
  for (int e = t; e < 1600; e += 256) {
    int bl = e / 50, l = e - bl * 50;
    sb[bl * 153 + 100 + l] = expr[(size_t)(b0 + bl) * 50 + l];
  }
  __syncthreads();

  if (t < 32) {
    int b = b0 + t;
    float jnt[5][3];
    {
      const f32x4* J4 = (const f32x4*)(js2 + 150 * 16);
      f32x4 A = J4[0], Bq = J4[1], Cq = J4[2], Dq = J4[3];
      jnt[0][0] = A.x;  jnt[0][1] = A.y;  jnt[0][2] = A.z;
      jnt[1][0] = A.w;  jnt[1][1] = Bq.x; jnt[1][2] = Bq.y;
      jnt[2][0] = Bq.z; jnt[2][1] = Bq.w; jnt[2][2] = Cq.x;
      jnt[3][0] = Cq.y; jnt[3][1] = Cq.z; jnt[3][2] = Cq.w;
      jnt[4][0] = Dq.x; jnt[4][1] = Dq.y; jnt[4][2] = Dq.z;
    }
    for (int l = 0; l < 150; ++l) {
      const f32x4* J4 = (const f32x4*)(js2 + l * 16);
      f32x4 A = J4[0], Bq = J4[1], Cq = J4[2], Dq = J4[3];
      float beta = sb[t * 153 + l];
      jnt[0][0] = fmaf(beta, A.x,  jnt[0][0]);
      jnt[0][1] = fmaf(beta, A.y,  jnt[0][1]);
      jnt[0][2] = fmaf(beta, A.z,  jnt[0][2]);
      jnt[1][0] = fmaf(beta, A.w,  jnt[1][0]);
      jnt[1][1] = fmaf(beta, Bq.x, jnt[1][1]);
      jnt[1][2] = fmaf(beta, Bq.y, jnt[1][2]);
      jnt[2][0] = fmaf(beta, Bq.z, jnt[2][0]);
      jnt[2][1] = fmaf(beta, Bq.w, jnt[2][1]);
      jnt[2][2] = fmaf(beta, Cq.x, jnt[2][2]);
      jnt[3][0] = fmaf(beta, Cq.y, jnt[3][0]);
      jnt[3][1] = fmaf(beta, Cq.z, jnt[3][1]);
      jnt[3][2] = fmaf(beta, Cq.w, jnt[3][2]);
      jnt[4][0] = fmaf(beta, Dq.x, jnt[4][0]);
      jnt[4][1] = fmaf(beta, Dq.y, jnt[4][1]);
      jnt[4][2] = fmaf(beta, Dq.z, jnt[4][2]);
    }
    float fp[5][3];
    fp[0][0] = pose[b * 6 + 0]; fp[0][1] = pose[b * 6 + 1]; fp[0][2] = pose[b * 6 + 2];
    fp[1][0] = 0.f; fp[1][1] = 0.f; fp[1][2] = 0.f;
    fp[2][0] = pose[b * 6 + 3]; fp[2][1] = pose[b * 6 + 4]; fp[2][2] = pose[b * 6 + 5];
    fp[3][0] = eyep[b * 6 + 0]; fp[3][1] = eyep[b * 6 + 1]; fp[3][2] = eyep[b * 6 + 2];
    fp[4][0] = eyep[b * 6 + 3]; fp[4][1] = eyep[b * 6 + 4]; fp[4][2] = eyep[b * 6 + 5];
    float R[5][9];
#pragma unroll
    for (int j = 0; j < 5; ++j) rodrigues9(fp[j][0], fp[j][1], fp[j][2], R[j]);
#pragma unroll
    for (int j = 1; j < 5; ++j)
#pragma unroll
      for (int r = 0; r < 9; ++r) {
        float id = (r == 0 || r == 4 || r == 8) ? 1.f : 0.f;
        pfs[t * 36 + (j - 1) * 9 + r] = R[j][r] - id;
      }
    float rel[5][3];
#pragma unroll
    for (int c = 0; c < 3; ++c) {
      rel[0][c] = jnt[0][c];
      rel[1][c] = jnt[1][c] - jnt[0][c];
      rel[2][c] = jnt[2][c] - jnt[1][c];
      rel[3][c] = jnt[3][c] - jnt[1][c];
      rel[4][c] = jnt[4][c] - jnt[1][c];
    }
    float GR[5][9], Gt[5][3];
#pragma unroll
    for (int r = 0; r < 9; ++r) GR[0][r] = R[0][r];
#pragma unroll
    for (int c = 0; c < 3; ++c) Gt[0][c] = rel[0][c];
    const int par[5] = {0, 0, 1, 1, 1};
#pragma unroll
    for (int j = 1; j < 5; ++j) {
      int p = par[j];
#pragma unroll
      for (int r = 0; r < 3; ++r) {
#pragma unroll
        for (int cc = 0; cc < 3; ++cc)
          GR[j][r * 3 + cc] = GR[p][r * 3 + 0] * R[j][0 + cc] +
                              GR[p][r * 3 + 1] * R[j][3 + cc] +
                              GR[p][r * 3 + 2] * R[j][6 + cc];
        Gt[j][r] = Gt[p][r] + GR[p][r * 3 + 0] * rel[j][0] +
                              GR[p][r * 3 + 1] * rel[j][1] +
                              GR[p][r * 3 + 2] * rel[j][2];
      }
    }
#pragma unroll
    for (int j = 0; j < 5; ++j)
#pragma unroll
      for (int r = 0; r < 3; ++r) {
        float tj = Gt[j][r] - (GR[j][r * 3 + 0] * jnt[j][0] +
                               GR[j][r * 3 + 1] * jnt[j][1] +
                               GR[j][r * 3 + 2] * jnt[j][2]);
        Arel[b * 60 + j * 12 + r * 4 + 0] = GR[j][r * 3 + 0];
        Arel[b * 60 + j * 12 + r * 4 + 1] = GR[j][r * 3 + 1];
        Arel[b * 60 + j * 12 + r * 4 + 2] = GR[j][r * 3 + 2];
        Arel[b * 60 + j * 12 + r * 4 + 3] = tj;
      }
    float Ra[9], Rb[9];
    rodrigues9(fp[1][0], fp[1][1], fp[1][2], Ra);
    rodrigues9(fp[0][0], fp[0][1], fp[0][2], Rb);
    float r00 = Rb[0] * Ra[0] + Rb[1] * Ra[3] + Rb[2] * Ra[6];
    float r10 = Rb[3] * Ra[0] + Rb[4] * Ra[3] + Rb[5] * Ra[6];
    float r20 = Rb[6] * Ra[0] + Rb[7] * Ra[3] + Rb[8] * Ra[6];
    float sy = sqrtf(r00 * r00 + r10 * r10);
    float ydeg = atan2f(-r20, sy) * 57.29577951308232f;
    int y = (int)rintf(fminf(ydeg, 39.0f));
    if (y < 0) y = (y < -39) ? 78 : (39 - y);
    yrot[b] = y;
  }
  __syncthreads();

#pragma unroll
  for (int it = 0; it < 12; ++it) {
    int e = t + it * 256;
    int bl = e / 96, d = e - bl * 96;
    unsigned int wv;
    if (d < 75) {
      wv = (unsigned int)f2bf(sb[bl * 153 + 2 * d]) |
           ((unsigned int)f2bf(sb[bl * 153 + 2 * d + 1]) << 16);
    } else if (d < 93) {
      wv = (unsigned int)f2bf(pfs[bl * 36 + (d - 75) * 2]) |
           ((unsigned int)f2bf(pfs[bl * 36 + (d - 75) * 2 + 1]) << 16);
    } else {
      wv = 0u;
    }
    atm_u[(size_t)(b0 + bl) * 96 + d] = wv;
  }
}

// ---------------- k_main: bf16 GEMM (64b x 96n, K=192) + b-major LBS epilogue ----------------
// LDS 39424 B -> 4 blocks/CU. Staging: 9 uint4 (BTn prepped). Epilogue: 1 thread = 1 batch,
// Arel 15 loads/thread once; lbw/vt from LDS tile; P via stride-66 LDS transpose.
__global__ __launch_bounds__(256) void k_main(
    const unsigned short* __restrict__ BTn, const unsigned short* __restrict__ ATm,
    const float* __restrict__ Arel, const float* __restrict__ vtempl,
    const float* __restrict__ lbw, float* __restrict__ out) {
  __shared__ __align__(16) unsigned char smem[39424];
  unsigned short* Bs = (unsigned short*)smem;     // 96 rows x 200 bf16 (38400 B)
  float* Pf   = (float*)smem;                     // after MFMA: 96 rows x stride 66 f32
  float* lbwT = (float*)(smem + 38400);           // 32*5
  float* vtT  = (float*)(smem + 39040);           // 32*3

  // swizzle: same nb -> bids stride 8 -> same XCD for BTn L2 reuse
  const int bid = blockIdx.x;
  const int r8 = bid & 7, q = bid >> 3;
  const int mb = q & 7, nbh = q >> 3;
  const int nb = (nbh << 3) | r8;
  if (nb >= 157) return;

  const int t = threadIdx.x;
  const int w = t >> 6, L = t & 63;
  const int wm = w >> 1, wn = w & 1;
  const int lr = L & 15, lq = L >> 4;

  // ---- stage B tile (36,864 contiguous bytes) + lbw/vt tiles ----
  const unsigned short* bsrc = BTn + (size_t)nb * 96 * 192;
  uint4 bst[9];
#pragma unroll
  for (int it = 0; it < 9; ++it)
    bst[it] = *(const uint4*)(bsrc + ((size_t)(t + it * 256)) * 8);
#pragma unroll
  for (int it = 0; it < 9; ++it) {
    int e = t + it * 256;
    int row = e / 24, col = e - row * 24;
    *(uint4*)(smem + row * 400 + col * 16) = bst[it];
  }
  if (t < 160) {
    int vl = t / 5, j = t - vl * 5;
    int v = nb * 32 + vl;
    lbwT[t] = (v < cV) ? lbw[v * 5 + j] : 0.f;
  }
  if (t < 96) {
    int vl = t / 3, c = t - vl * 3;
    int v = nb * 32 + vl;
    vtT[t] = (v < cV) ? vtempl[v * 3 + c] : 0.f;
  }
  __syncthreads();

  // ---- MFMA with rolling A prefetch ----
  f32x4 acc[2][3];
#pragma unroll
  for (int mt = 0; mt < 2; ++mt)
#pragma unroll
    for (int nt = 0; nt < 3; ++nt) acc[mt][nt] = (f32x4){0.f, 0.f, 0.f, 0.f};

  const unsigned short* abase = ATm + ((size_t)mb * 64 + wm * 32 + lr) * 192 + lq * 8;
  short8 af0 = *(const short8*)(abase);
  short8 af1 = *(const short8*)(abase + 16 * 192);
#pragma unroll
  for (int ks = 0; ks < 6; ++ks) {
    short8 nf0, nf1;
    if (ks < 5) {
      nf0 = *(const short8*)(abase + (ks + 1) * 32);
      nf1 = *(const short8*)(abase + 16 * 192 + (ks + 1) * 32);
    }
    const int ko = ks * 32 + lq * 8;
    short8 bf[3];
#pragma unroll
    for (int nt = 0; nt < 3; ++nt)
      bf[nt] = *(const short8*)(Bs + (wn * 48 + nt * 16 + lr) * 200 + ko);
#pragma unroll
    for (int nt = 0; nt < 3; ++nt) {
      acc[0][nt] = __builtin_amdgcn_mfma_f32_16x16x32_bf16(af0, bf[nt], acc[0][nt], 0, 0, 0);
      acc[1][nt] = __builtin_amdgcn_mfma_f32_16x16x32_bf16(af1, bf[nt], acc[1][nt], 0, 0, 0);
    }
    af0 = nf0; af1 = nf1;
  }

  // ---- Arel row for this thread's batch (15 coalesced loads, overlap the barrier) ----
  const int b_loc = t >> 2, part = t & 3;
  const float* qb = Arel + ((size_t)mb * 64 + b_loc) * 60;
  f32x4 ar[15];
#pragma unroll
  for (int r = 0; r < 15; ++r) ar[r] = *(const f32x4*)(qb + 4 * r);

  __syncthreads();   // all Bs reads done; safe to overwrite LDS with Pf

  // ---- acc -> Pf[n_loc][b] (stride 66: conflict-free both directions) ----
#pragma unroll
  for (int mt = 0; mt < 2; ++mt)
#pragma unroll
    for (int nt = 0; nt < 3; ++nt) {
      int n_loc = wn * 48 + nt * 16 + lr;
      int m = wm * 32 + mt * 16 + lq * 4;
      *(f32x4*)(Pf + n_loc * 66 + m) = acc[mt][nt];
    }
  __syncthreads();

  // ---- b-major LBS epilogue: thread owns batch b_loc, vertices part*8..part*8+7 ----
#pragma unroll
  for (int i = 0; i < 8; ++i) {
    const int vl = part * 8 + i;
    float px = Pf[(vl * 3 + 0) * 66 + b_loc] + vtT[vl * 3 + 0];
    float py = Pf[(vl * 3 + 1) * 66 + b_loc] + vtT[vl * 3 + 1];
    float pz = Pf[(vl * 3 + 2) * 66 + b_loc] + vtT[vl * 3 + 2];
    float o0 = 0.f, o1 = 0.f, o2 = 0.f;
#pragma unroll
    for (int j = 0; j < 5; ++j) {
      f32x4 q0 = ar[3 * j + 0], q1 = ar[3 * j + 1], q2 = ar[3 * j + 2];
      float s0 = q0.x * px + q0.y * py + q0.z * pz + q0.w;
      float s1 = q1.x * px + q1.y * py + q1.z * pz + q1.w;
      float s2 = q2.x * px + q2.y * py + q2.z * pz + q2.w;
      float wj = lbwT[vl * 5 + j];
      o0 = fmaf(wj, s0, o0);
      o1 = fmaf(wj, s1, o1);
      o2 = fmaf(wj, s2, o2);
    }
    const int v = nb * 32 + vl;
    if (v < cV) {
      size_t off = ((size_t)(mb * 64 + b_loc) * cV + v) * 3;
      out[off + 0] = o0;
      out[off + 1] = o1;
      out[off + 2] = o2;
    }
  }
}

// ---------------- k_lmk: barycentric landmark gather, 1 thread per (b, l, which) ----------------
__global__ void k_lmk(const float* __restrict__ verts, const int* __restrict__ faces,
                      const int* __restrict__ lmkf, const float* __restrict__ lmkb,
                      const int* __restrict__ dynf, const float* __restrict__ dynb,
                      const int* __restrict__ fullf, const float* __restrict__ fullb,
                      const int* __restrict__ yrot, float* __restrict__ out) {
  int id = blockIdx.x * 256 + threadIdx.x;
  if (id >= cB * cLF * 2) return;
  int sel = id & 1;
  int r = id >> 1;
  int b = r / cLF, l = r - b * cLF;
  const float* vb = verts + (size_t)b * cV * 3;
  int f; float w0, w1, w2; size_t o;
  if (sel == 0) {
    if (l < cLD) {
      int yb = yrot[b];
      f = dynf[yb * cLD + l];
      const float* bp = dynb + ((size_t)yb * cLD + l) * 3;
      w0 = bp[0]; w1 = bp[1]; w2 = bp[2];
    } else {
      f = lmkf[l - cLD];
      const float* bp = lmkb + (size_t)(l - cLD) * 3;
      w0 = bp[0]; w1 = bp[1]; w2 = bp[2];
    }
    o = OUT_V + ((size_t)b * cLF + l) * 3;
  } else {
    f = fullf[l];
    const float* bp = fullb + (size_t)l * 3;
    w0 = bp[0]; w1 = bp[1]; w2 = bp[2];
    o = OUT_V + OUT_L + ((size_t)b * cLF + l) * 3;
  }
  int i0 = faces[f * 3 + 0] * 3, i1 = faces[f * 3 + 1] * 3, i2 = faces[f * 3 + 2] * 3;
  out[o + 0] = w0 * vb[i0 + 0] + w1 * vb[i1 + 0] + w2 * vb[i2 + 0];
  out[o + 1] = w0 * vb[i0 + 1] + w1 * vb[i1 + 1] + w2 * vb[i2 + 1];
  out[o + 2] = w0 * vb[i0 + 2] + w1 * vb[i1 + 2] + w2 * vb[i2 + 2];
}

// ---------------- launch ----------------
extern "C" void kernel_launch(void* const* d_in, const int* in_sizes, int n_in,
                              void* d_out, int out_size, void* d_ws, size_t ws_size,
                              hipStream_t stream) {
  (void)in_sizes; (void)n_in; (void)out_size; (void)ws_size;
  const float* shp  = (const float*)d_in[0];
  const float* expr = (const float*)d_in[1];
  const float* pose = (const float*)d_in[2];
  const float* eyep = (const float*)d_in[3];
  const float* vt   = (const float*)d_in[4];
  const float* sd   = (const float*)d_in[5];
  const float* pd   = (const float*)d_in[6];
  const float* jreg = (const float*)d_in[7];
  const float* lbw  = (const float*)d_in[8];
  const int*   fcs  = (const int*)d_in[9];
  const int*   lmkf = (const int*)d_in[10];
  const float* lmkb = (const float*)d_in[11];
  const int*   dynf = (const int*)d_in[12];
  const float* dynb = (const float*)d_in[13];
  const int*   fullf= (const int*)d_in[14];
  const float* fullb= (const float*)d_in[15];
  float* out = (float*)d_out;
  float* ws  = (float*)d_ws;

  unsigned int*   btn  = (unsigned int*)(ws + WS_BTN);
  unsigned short* ATm  = (unsigned short*)(ws + WS_ATM);
  float* JS2    = ws + WS_JS2;
  float* Arel   = ws + WS_AREL;
  int*   yrot   = (int*)(ws + WS_YROT);
  float* JSpart = ws + WS_JSPART;

  k_aux<<<864, 512, 0, stream>>>(sd, pd, jreg, vt, btn, JSpart);
  k_jsred<<<71, 256, 0, stream>>>(JSpart, JS2);
  k_batch<<<16, 256, 0, stream>>>(shp, expr, pose, eyep, JS2, Arel, yrot,
                                  (unsigned int*)ATm);
  k_main<<<1280, 256, 0, stream>>>((unsigned short*)btn, ATm, Arel, vt, lbw, out);
  k_lmk<<<272, 256, 0, stream>>>(out, fcs, lmkf, lmkb, dynf, dynb, fullf, fullb, yrot, out);
}

// Round 9
// 181.298 us; speedup vs baseline: 1.2801x; 1.0169x over previous
//
#include <hip/hip_runtime.h>
#include <cstddef>
#include <cstdint>

// ---------------- problem constants ----------------
#define cB   512
#define cV   5023
#define cS   100
#define cE   50
#define cJ   5
#define cLD  17
#define cLF  68

#define cV3    15069       // V*3
#define cNPAD  15072       // 157*96 padded N

#define OUT_V  ((size_t)cB * cV * 3)
#define OUT_L  ((size_t)cB * cLF * 3)

// ws layout (dword offsets)
#define WS_BTN    ((size_t)0)                      // 15072*96 dwords (bf16 x2)
#define WS_ATM    (WS_BTN + (size_t)cNPAD * 96)    // 512*96 dwords
#define WS_JS2    (WS_ATM + 49152)                 // 2432 floats
#define WS_AREL   (WS_JS2 + 2432)                  // 512*60 floats
#define WS_YROT   (WS_AREL + 30720)                // 512 ints
#define WS_JSPART (WS_YROT + 512)                  // 314*2272 floats

typedef __attribute__((ext_vector_type(8))) short short8;
typedef __attribute__((ext_vector_type(4))) float f32x4;

// fp32 -> bf16 round-to-nearest-even
__device__ __forceinline__ unsigned short f2bf(float x) {
  unsigned int u = __float_as_uint(x);
  u = (u + 0x7fffu + ((u >> 16) & 1u)) >> 16;
  return (unsigned short)u;
}

// ---------------- rodrigues (matches jax reference in fp32) ----------------
__device__ __forceinline__ void rodrigues9(float rx, float ry, float rz, float* R) {
  float a0 = rx + 1e-8f, a1 = ry + 1e-8f, a2 = rz + 1e-8f;
  float angle = sqrtf(a0 * a0 + a1 * a1 + a2 * a2);
  float inv = 1.0f / angle;
  float x = rx * inv, y = ry * inv, z = rz * inv;
  float s = sinf(angle), c = cosf(angle);
  float t = 1.0f - c;
  float xy = x * y, xz = x * z, yz = y * z;
  R[0] = 1.0f - t * (y * y + z * z);
  R[1] = -s * z + t * xy;
  R[2] =  s * y + t * xz;
  R[3] =  s * z + t * xy;
  R[4] = 1.0f - t * (x * x + z * z);
  R[5] = -s * x + t * yz;
  R[6] = -s * y + t * xz;
  R[7] =  s * x + t * yz;
  R[8] = 1.0f - t * (x * x + y * y);
}

// ---------------- k_aux: blocks 0..313 JS partials (16 v); 314..549 bf16 BTn rows ----------
__global__ __launch_bounds__(512) void k_aux(
    const float* __restrict__ sd, const float* __restrict__ pd,
    const float* __restrict__ jreg, const float* __restrict__ vt,
    unsigned int* __restrict__ btn_u, float* __restrict__ JSpart) {
  __shared__ __align__(16) unsigned char sm[44032];  // sdt 64*152*4 @0; pdt 64*38*2 @38912
  float* sdt = (float*)sm;
  unsigned short* pdt = (unsigned short*)(sm + 38912);
  const int t = threadIdx.x;
  const int bid = blockIdx.x;
  if (bid < 314) {
    if (t >= 453) return;
    int c = t / 151, l = t - c * 151;
    int v0 = bid * 16;
    float acc[5] = {0.f, 0.f, 0.f, 0.f, 0.f};
#pragma unroll 8
    for (int vi = 0; vi < 16; ++vi) {
      int v = v0 + vi;
      bool ok = (v < cV);
      int vc = ok ? v : 0;
      float x;
      if (l < 150) x = ok ? sd[(size_t)(v * 3 + c) * 150 + l] : 0.f;
      else         x = ok ? vt[v * 3 + c] : 0.f;
#pragma unroll
      for (int j = 0; j < 5; ++j)
        acc[j] = fmaf(jreg[j * cV + vc], x, acc[j]);
    }
#pragma unroll
    for (int j = 0; j < 5; ++j)
      JSpart[(size_t)bid * 2272 + (j * 3 + c) * 151 + l] = acc[j];
  } else {
    const int n0 = (bid - 314) * 64;
    // sd rows (linear, coalesced)
    for (int idx = t; idx < 9600; idx += 512) {
      size_t g = (size_t)n0 * 150 + idx;
      float v = (g < (size_t)cV3 * 150) ? sd[g] : 0.f;
      int row = idx / 150, col = idx - row * 150;
      sdt[row * 152 + col] = v;
    }
    // pd columns (coalesced over n)
    for (int e = t; e < 2304; e += 512) {
      int kk = e >> 6, ln = e & 63;
      int n = n0 + ln;
      pdt[ln * 38 + kk] = f2bf((n < cV3) ? pd[(size_t)kk * cV3 + n] : 0.f);
    }
    __syncthreads();
    // emit BTn rows (96 dwords each), coalesced
    for (int e = t; e < 6144; e += 512) {
      int row = e / 96, d = e - row * 96;
      int n = n0 + row;
      if (n < cNPAD) {
        unsigned int wv;
        if (d < 75) {
          wv = (unsigned int)f2bf(sdt[row * 152 + 2 * d]) |
               ((unsigned int)f2bf(sdt[row * 152 + 2 * d + 1]) << 16);
        } else if (d < 93) {
          int p = (d - 75) * 2;
          wv = (unsigned int)pdt[row * 38 + p] |
               ((unsigned int)pdt[row * 38 + p + 1] << 16);
        } else {
          wv = 0u;
        }
        btn_u[(size_t)n * 96 + d] = wv;
      }
    }
  }
}

// ---------------- k_jsred: 314 partials -> JS2[l][16]; 8 threads per element ----------------
__global__ __launch_bounds__(256) void k_jsred(const float* __restrict__ JSpart,
                                               float* __restrict__ JS2) {
  __shared__ float red[256];
  const int t = threadIdx.x;
  const int e = blockIdx.x * 32 + (t & 31);
  const int pg = t >> 5;
  float s = 0.f;
  if (e < 2265) {
#pragma unroll 8
    for (int p = pg; p < 314; p += 8)
      s += JSpart[(size_t)p * 2272 + e];
  }
  red[t] = s;
  __syncthreads();
  if (t < 128) red[t] += red[t + 128];
  __syncthreads();
  if (t < 64) red[t] += red[t + 64];
  __syncthreads();
  if (t < 32) {
    float v = red[t] + red[t + 32];
    if (e < 2265) {
      int jc = e / 151, l = e - jc * 151;
      JS2[l * 16 + jc] = v;
    }
  }
}

// ---------------- k_batch: joints, rot mats, chain, A_rel, y_rot + ATm bf16 rows ----------
__global__ __launch_bounds__(256) void k_batch(
    const float* __restrict__ shp, const float* __restrict__ expr,
    const float* __restrict__ pose, const float* __restrict__ eyep,
    const float* __restrict__ JS2g, float* __restrict__ Arel,
    int* __restrict__ yrot, unsigned int* __restrict__ atm_u) {
  __shared__ float js2[151 * 16];
  __shared__ float sb[32 * 153];
  __shared__ float pfs[32 * 36];
  const int t = threadIdx.x;
  const int b0 = blockIdx.x * 32;
  for (int i = t; i < 151 * 16; i += 256) js2[i] = JS2g[i];
  for (int e = t; e < 3200; e += 256) {
    int bl = e / 100, l = e - bl * 100;
    sb[bl * 153 + l] = shp[(size_t)(b0 + bl) * 100 + l];
  }
  for (int e = t; e < 1600; e += 256) {
    int bl = e / 50, l = e - bl * 50;
    sb[bl * 153 + 100 + l] = expr[(size_t)(b0 + bl) * 50 + l];
  }
  __syncthreads();

  if (t < 32) {
    int b = b0 + t;
    float jnt[5][3];
    {
      const f32x4* J4 = (const f32x4*)(js2 + 150 * 16);
      f32x4 A = J4[0], Bq = J4[1], Cq = J4[2], Dq = J4[3];
      jnt[0][0] = A.x;  jnt[0][1] = A.y;  jnt[0][2] = A.z;
      jnt[1][0] = A.w;  jnt[1][1] = Bq.x; jnt[1][2] = Bq.y;
      jnt[2][0] = Bq.z; jnt[2][1] = Bq.w; jnt[2][2] = Cq.x;
      jnt[3][0] = Cq.y; jnt[3][1] = Cq.z; jnt[3][2] = Cq.w;
      jnt[4][0] = Dq.x; jnt[4][1] = Dq.y; jnt[4][2] = Dq.z;
    }
    for (int l = 0; l < 150; ++l) {
      const f32x4* J4 = (const f32x4*)(js2 + l * 16);
      f32x4 A = J4[0], Bq = J4[1], Cq = J4[2], Dq = J4[3];
      float beta = sb[t * 153 + l];
      jnt[0][0] = fmaf(beta, A.x,  jnt[0][0]);
      jnt[0][1] = fmaf(beta, A.y,  jnt[0][1]);
      jnt[0][2] = fmaf(beta, A.z,  jnt[0][2]);
      jnt[1][0] = fmaf(beta, A.w,  jnt[1][0]);
      jnt[1][1] = fmaf(beta, Bq.x, jnt[1][1]);
      jnt[1][2] = fmaf(beta, Bq.y, jnt[1][2]);
      jnt[2][0] = fmaf(beta, Bq.z, jnt[2][0]);
      jnt[2][1] = fmaf(beta, Bq.w, jnt[2][1]);
      jnt[2][2] = fmaf(beta, Cq.x, jnt[2][2]);
      jnt[3][0] = fmaf(beta, Cq.y, jnt[3][0]);
      jnt[3][1] = fmaf(beta, Cq.z, jnt[3][1]);
      jnt[3][2] = fmaf(beta, Cq.w, jnt[3][2]);
      jnt[4][0] = fmaf(beta, Dq.x, jnt[4][0]);
      jnt[4][1] = fmaf(beta, Dq.y, jnt[4][1]);
      jnt[4][2] = fmaf(beta, Dq.z, jnt[4][2]);
    }
    float fp[5][3];
    fp[0][0] = pose[b * 6 + 0]; fp[0][1] = pose[b * 6 + 1]; fp[0][2] = pose[b * 6 + 2];
    fp[1][0] = 0.f; fp[1][1] = 0.f; fp[1][2] = 0.f;
    fp[2][0] = pose[b * 6 + 3]; fp[2][1] = pose[b * 6 + 4]; fp[2][2] = pose[b * 6 + 5];
    fp[3][0] = eyep[b * 6 + 0]; fp[3][1] = eyep[b * 6 + 1]; fp[3][2] = eyep[b * 6 + 2];
    fp[4][0] = eyep[b * 6 + 3]; fp[4][1] = eyep[b * 6 + 4]; fp[4][2] = eyep[b * 6 + 5];
    float R[5][9];
#pragma unroll
    for (int j = 0; j < 5; ++j) rodrigues9(fp[j][0], fp[j][1], fp[j][2], R[j]);
#pragma unroll
    for (int j = 1; j < 5; ++j)
#pragma unroll
      for (int r = 0; r < 9; ++r) {
        float id = (r == 0 || r == 4 || r == 8) ? 1.f : 0.f;
        pfs[t * 36 + (j - 1) * 9 + r] = R[j][r] - id;
      }
    float rel[5][3];
#pragma unroll
    for (int c = 0; c < 3; ++c) {
      rel[0][c] = jnt[0][c];
      rel[1][c] = jnt[1][c] - jnt[0][c];
      rel[2][c] = jnt[2][c] - jnt[1][c];
      rel[3][c] = jnt[3][c] - jnt[1][c];
      rel[4][c] = jnt[4][c] - jnt[1][c];
    }
    float GR[5][9], Gt[5][3];
#pragma unroll
    for (int r = 0; r < 9; ++r) GR[0][r] = R[0][r];
#pragma unroll
    for (int c = 0; c < 3; ++c) Gt[0][c] = rel[0][c];
    const int par[5] = {0, 0, 1, 1, 1};
#pragma unroll
    for (int j = 1; j < 5; ++j) {
      int p = par[j];
#pragma unroll
      for (int r = 0; r < 3; ++r) {
#pragma unroll
        for (int cc = 0; cc < 3; ++cc)
          GR[j][r * 3 + cc] = GR[p][r * 3 + 0] * R[j][0 + cc] +
                              GR[p][r * 3 + 1] * R[j][3 + cc] +
                              GR[p][r * 3 + 2] * R[j][6 + cc];
        Gt[j][r] = Gt[p][r] + GR[p][r * 3 + 0] * rel[j][0] +
                              GR[p][r * 3 + 1] * rel[j][1] +
                              GR[p][r * 3 + 2] * rel[j][2];
      }
    }
#pragma unroll
    for (int j = 0; j < 5; ++j)
#pragma unroll
      for (int r = 0; r < 3; ++r) {
        float tj = Gt[j][r] - (GR[j][r * 3 + 0] * jnt[j][0] +
                               GR[j][r * 3 + 1] * jnt[j][1] +
                               GR[j][r * 3 + 2] * jnt[j][2]);
        Arel[b * 60 + j * 12 + r * 4 + 0] = GR[j][r * 3 + 0];
        Arel[b * 60 + j * 12 + r * 4 + 1] = GR[j][r * 3 + 1];
        Arel[b * 60 + j * 12 + r * 4 + 2] = GR[j][r * 3 + 2];
        Arel[b * 60 + j * 12 + r * 4 + 3] = tj;
      }
    float Ra[9], Rb[9];
    rodrigues9(fp[1][0], fp[1][1], fp[1][2], Ra);
    rodrigues9(fp[0][0], fp[0][1], fp[0][2], Rb);
    float r00 = Rb[0] * Ra[0] + Rb[1] * Ra[3] + Rb[2] * Ra[6];
    float r10 = Rb[3] * Ra[0] + Rb[4] * Ra[3] + Rb[5] * Ra[6];
    float r20 = Rb[6] * Ra[0] + Rb[7] * Ra[3] + Rb[8] * Ra[6];
    float sy = sqrtf(r00 * r00 + r10 * r10);
    float ydeg = atan2f(-r20, sy) * 57.29577951308232f;
    int y = (int)rintf(fminf(ydeg, 39.0f));
    if (y < 0) y = (y < -39) ? 78 : (39 - y);
    yrot[b] = y;
  }
  __syncthreads();

#pragma unroll
  for (int it = 0; it < 12; ++it) {
    int e = t + it * 256;
    int bl = e / 96, d = e - bl * 96;
    unsigned int wv;
    if (d < 75) {
      wv = (unsigned int)f2bf(sb[bl * 153 + 2 * d]) |
           ((unsigned int)f2bf(sb[bl * 153 + 2 * d + 1]) << 16);
    } else if (d < 93) {
      wv = (unsigned int)f2bf(pfs[bl * 36 + (d - 75) * 2]) |
           ((unsigned int)f2bf(pfs[bl * 36 + (d - 75) * 2 + 1]) << 16);
    } else {
      wv = 0u;
    }
    atm_u[(size_t)(b0 + bl) * 96 + d] = wv;
  }
}

// ---------------- k_main: 2 nb-tiles per block; bf16 GEMM + b-major LBS epilogue ----------------
// 640 blocks = 80 nb-pairs x 8 mb. LDS 39424 B. Arel/A-base hoisted across the 2 tiles.
__global__ __launch_bounds__(256) void k_main(
    const unsigned short* __restrict__ BTn, const unsigned short* __restrict__ ATm,
    const float* __restrict__ Arel, const float* __restrict__ vtempl,
    const float* __restrict__ lbw, float* __restrict__ out) {
  __shared__ __align__(16) unsigned char smem[39424];
  unsigned short* Bs = (unsigned short*)smem;     // 96 rows x 200 bf16 (38400 B)
  float* Pf   = (float*)smem;                     // after MFMA: 96 rows x stride 66 f32 (25344 B)
  float* lbwT = (float*)(smem + 38400);           // 32*5
  float* vtT  = (float*)(smem + 39040);           // 32*3

  // bid = ph*64 + mb*8 + r8 ; pair p = ph*8 + r8 -> same pair => same XCD (r8)
  const int bid = blockIdx.x;
  const int ph = bid >> 6, mb = (bid >> 3) & 7, r8 = bid & 7;
  const int p = ph * 8 + r8;

  const int t = threadIdx.x;
  const int w = t >> 6, L = t & 63;
  const int wm = w >> 1, wn = w & 1;
  const int lr = L & 15, lq = L >> 4;
  const int b_loc = t >> 2, part = t & 3;

  // hoisted: Arel row for this thread's batch (same for both tiles)
  const float* qb = Arel + ((size_t)mb * 64 + b_loc) * 60;
  f32x4 ar[15];
#pragma unroll
  for (int r = 0; r < 15; ++r) ar[r] = *(const f32x4*)(qb + 4 * r);
  const unsigned short* abase = ATm + ((size_t)mb * 64 + wm * 32 + lr) * 192 + lq * 8;

#pragma unroll 1
  for (int i = 0; i < 2; ++i) {
    const int nb = 2 * p + i;
    if (nb >= 157) continue;          // block-uniform -> barrier-safe
    if (i) __syncthreads();           // protect LDS reuse across tiles

    // ---- stage B tile (36,864 contiguous bytes) + lbw/vt tiles ----
    const unsigned short* bsrc = BTn + (size_t)nb * 96 * 192;
    uint4 bst[9];
#pragma unroll
    for (int it = 0; it < 9; ++it)
      bst[it] = *(const uint4*)(bsrc + ((size_t)(t + it * 256)) * 8);
#pragma unroll
    for (int it = 0; it < 9; ++it) {
      int e = t + it * 256;
      int row = e / 24, col = e - row * 24;
      *(uint4*)(smem + row * 400 + col * 16) = bst[it];
    }
    if (t < 160) {
      int vl = t / 5, j = t - vl * 5;
      int v = nb * 32 + vl;
      lbwT[t] = (v < cV) ? lbw[v * 5 + j] : 0.f;
    }
    if (t < 96) {
      int vl = t / 3, c = t - vl * 3;
      int v = nb * 32 + vl;
      vtT[t] = (v < cV) ? vtempl[v * 3 + c] : 0.f;
    }
    __syncthreads();

    // ---- MFMA with rolling A prefetch ----
    f32x4 acc[2][3];
#pragma unroll
    for (int mt = 0; mt < 2; ++mt)
#pragma unroll
      for (int nt = 0; nt < 3; ++nt) acc[mt][nt] = (f32x4){0.f, 0.f, 0.f, 0.f};

    short8 af0 = *(const short8*)(abase);
    short8 af1 = *(const short8*)(abase + 16 * 192);
#pragma unroll
    for (int ks = 0; ks < 6; ++ks) {
      short8 nf0, nf1;
      if (ks < 5) {
        nf0 = *(const short8*)(abase + (ks + 1) * 32);
        nf1 = *(const short8*)(abase + 16 * 192 + (ks + 1) * 32);
      }
      const int ko = ks * 32 + lq * 8;
      short8 bf[3];
#pragma unroll
      for (int nt = 0; nt < 3; ++nt)
        bf[nt] = *(const short8*)(Bs + (wn * 48 + nt * 16 + lr) * 200 + ko);
#pragma unroll
      for (int nt = 0; nt < 3; ++nt) {
        acc[0][nt] = __builtin_amdgcn_mfma_f32_16x16x32_bf16(af0, bf[nt], acc[0][nt], 0, 0, 0);
        acc[1][nt] = __builtin_amdgcn_mfma_f32_16x16x32_bf16(af1, bf[nt], acc[1][nt], 0, 0, 0);
      }
      af0 = nf0; af1 = nf1;
    }
    __syncthreads();   // all Bs reads done; safe to overwrite LDS with Pf

    // ---- acc -> Pf[n_loc][b] (stride 66: conflict-free both directions) ----
#pragma unroll
    for (int mt = 0; mt < 2; ++mt)
#pragma unroll
      for (int nt = 0; nt < 3; ++nt) {
        int n_loc = wn * 48 + nt * 16 + lr;
        int m = wm * 32 + mt * 16 + lq * 4;
        *(f32x4*)(Pf + n_loc * 66 + m) = acc[mt][nt];
      }
    __syncthreads();

    // ---- b-major LBS epilogue: thread owns batch b_loc, vertices part*8..part*8+7 ----
#pragma unroll
    for (int ii = 0; ii < 8; ++ii) {
      const int vl = part * 8 + ii;
      float px = Pf[(vl * 3 + 0) * 66 + b_loc] + vtT[vl * 3 + 0];
      float py = Pf[(vl * 3 + 1) * 66 + b_loc] + vtT[vl * 3 + 1];
      float pz = Pf[(vl * 3 + 2) * 66 + b_loc] + vtT[vl * 3 + 2];
      float o0 = 0.f, o1 = 0.f, o2 = 0.f;
#pragma unroll
      for (int j = 0; j < 5; ++j) {
        f32x4 q0 = ar[3 * j + 0], q1 = ar[3 * j + 1], q2 = ar[3 * j + 2];
        float s0 = q0.x * px + q0.y * py + q0.z * pz + q0.w;
        float s1 = q1.x * px + q1.y * py + q1.z * pz + q1.w;
        float s2 = q2.x * px + q2.y * py + q2.z * pz + q2.w;
        float wj = lbwT[vl * 5 + j];
        o0 = fmaf(wj, s0, o0);
        o1 = fmaf(wj, s1, o1);
        o2 = fmaf(wj, s2, o2);
      }
      const int v = nb * 32 + vl;
      if (v < cV) {
        size_t off = ((size_t)(mb * 64 + b_loc) * cV + v) * 3;
        out[off + 0] = o0;
        out[off + 1] = o1;
        out[off + 2] = o2;
      }
    }
  }
}

// ---------------- k_lmk: barycentric landmark gather, 1 thread per (b, l, which) ----------------
__global__ __launch_bounds__(512) void k_lmk(
    const float* __restrict__ verts, const int* __restrict__ faces,
    const int* __restrict__ lmkf, const float* __restrict__ lmkb,
    const int* __restrict__ dynf, const float* __restrict__ dynb,
    const int* __restrict__ fullf, const float* __restrict__ fullb,
    const int* __restrict__ yrot, float* __restrict__ out) {
  int id = blockIdx.x * 512 + threadIdx.x;
  if (id >= cB * cLF * 2) return;
  int sel = id & 1;
  int r = id >> 1;
  int b = r / cLF, l = r - b * cLF;
  const float* vb = verts + (size_t)b * cV * 3;
  int f; float w0, w1, w2; size_t o;
  if (sel == 0) {
    if (l < cLD) {
      int yb = yrot[b];
      f = dynf[yb * cLD + l];
      const float* bp = dynb + ((size_t)yb * cLD + l) * 3;
      w0 = bp[0]; w1 = bp[1]; w2 = bp[2];
    } else {
      f = lmkf[l - cLD];
      const float* bp = lmkb + (size_t)(l - cLD) * 3;
      w0 = bp[0]; w1 = bp[1]; w2 = bp[2];
    }
    o = OUT_V + ((size_t)b * cLF + l) * 3;
  } else {
    f = fullf[l];
    const float* bp = fullb + (size_t)l * 3;
    w0 = bp[0]; w1 = bp[1]; w2 = bp[2];
    o = OUT_V + OUT_L + ((size_t)b * cLF + l) * 3;
  }
  int i0 = faces[f * 3 + 0] * 3, i1 = faces[f * 3 + 1] * 3, i2 = faces[f * 3 + 2] * 3;
  out[o + 0] = w0 * vb[i0 + 0] + w1 * vb[i1 + 0] + w2 * vb[i2 + 0];
  out[o + 1] = w0 * vb[i0 + 1] + w1 * vb[i1 + 1] + w2 * vb[i2 + 1];
  out[o + 2] = w0 * vb[i0 + 2] + w1 * vb[i1 + 2] + w2 * vb[i2 + 2];
}

// ---------------- launch ----------------
extern "C" void kernel_launch(void* const* d_in, const int* in_sizes, int n_in,
                              void* d_out, int out_size, void* d_ws, size_t ws_size,
                              hipStream_t stream) {
  (void)in_sizes; (void)n_in; (void)out_size; (void)ws_size;
  const float* shp  = (const float*)d_in[0];
  const float* expr = (const float*)d_in[1];
  const float* pose = (const float*)d_in[2];
  const float* eyep = (const float*)d_in[3];
  const float* vt   = (const float*)d_in[4];
  const float* sd   = (const float*)d_in[5];
  const float* pd   = (const float*)d_in[6];
  const float* jreg = (const float*)d_in[7];
  const float* lbw  = (const float*)d_in[8];
  const int*   fcs  = (const int*)d_in[9];
  const int*   lmkf = (const int*)d_in[10];
  const float* lmkb = (const float*)d_in[11];
  const int*   dynf = (const int*)d_in[12];
  const float* dynb = (const float*)d_in[13];
  const int*   fullf= (const int*)d_in[14];
  const float* fullb= (const float*)d_in[15];
  float* out = (float*)d_out;
  float* ws  = (float*)d_ws;

  unsigned int*   btn  = (unsigned int*)(ws + WS_BTN);
  unsigned short* ATm  = (unsigned short*)(ws + WS_ATM);
  float* JS2    = ws + WS_JS2;
  float* Arel   = ws + WS_AREL;
  int*   yrot   = (int*)(ws + WS_YROT);
  float* JSpart = ws + WS_JSPART;

  k_aux<<<550, 512, 0, stream>>>(sd, pd, jreg, vt, btn, JSpart);
  k_jsred<<<71, 256, 0, stream>>>(JSpart, JS2);
  k_batch<<<16, 256, 0, stream>>>(shp, expr, pose, eyep, JS2, Arel, yrot,
                                  (unsigned int*)ATm);
  k_main<<<640, 256, 0, stream>>>((unsigned short*)btn, ATm, Arel, vt, lbw, out);
  k_lmk<<<136, 512, 0, stream>>>(out, fcs, lmkf, lmkb, dynf, dynb, fullf, fullb, yrot, out);
}